// Round 6
// baseline (2052.999 us; speedup 1.0000x reference)
//
#include <hip/hip_runtime.h>

// BitNet MLP: out = (silu(x@Gw^T * gs) * (x@Uw^T * us)) @ Dw^T * ds
// M=4096 tokens, K=4096 hidden, I=11008 inter. Ternary weights -> exact in bf16.
//
// R12: R9 GEMM core (16x16x32 MFMA frag pattern -- measured 0 bank conflicts;
// 32x32 variants measured a fixed 6.76e7 regardless of swizzle, reverted) +
// FUSED B DEQUANT: weight converts eliminated; B weights read as f32 inside
// the GEMM, truncated to bf16 (exact for ternary), ds_write'd into the LDS
// pipeline. Fixed R8's mistake with a dedicated wait budget:
//   iter kt: [LGKM(4); h0-MFMA; VMW(2); BAR;
//             issue Bf32(kt+3)->regs x4 + A-glds(kt+3) x2;   <- 3 iters slack
//             ds_write B(kt+2) from regs loaded at kt-1 x2;  <- landed by VMW(2)
//             frag reads (kt+1) x8; LGKM(10); h1-MFMA; ah1(kt+1) x4]
// lgkm stream/iter = [W2, R8, ah1 x4]: top LGKM(4) drains W+R (writes visible
// at next BAR), mid LGKM(10) drains only ah1. vmcnt stream/iter = [B x4, A x2]:
// VMW(2) drains through B(kt+2)+A(kt+1), leaves A(kt+2) flying.
// Buffer audit: writes hit (kt+2)&3 B-bufs; concurrent reads hit (kt+1)&3;
// glds hit (kt+3)&3 A-bufs -- disjoint. Only x -> bf16 convert remains.

typedef short short8 __attribute__((ext_vector_type(8)));
typedef float f32x4 __attribute__((ext_vector_type(4)));
typedef float fvec4 __attribute__((ext_vector_type(4)));
typedef unsigned short usvec4 __attribute__((ext_vector_type(4)));
typedef unsigned int u32x4 __attribute__((ext_vector_type(4)));

__device__ __forceinline__ unsigned short f2bf(float f) {
    unsigned int u = __float_as_uint(f);
    u += 0x7FFFu + ((u >> 16) & 1u);   // round-to-nearest-even
    return (unsigned short)(u >> 16);
}

// pack two f32 (a=low lane, b=high lane) into 2x bf16 by truncation --
// exact for ternary weights (+-1.0/0.0 have zero low mantissa bits).
__device__ __forceinline__ unsigned pkbf(unsigned a, unsigned b) {
    return (a >> 16) | (b & 0xFFFF0000u);
}

__global__ void cvt_f32_bf16(const fvec4* __restrict__ src,
                             usvec4* __restrict__ dst, long n4) {
    long stride = (long)gridDim.x * blockDim.x;
    for (long i = (long)blockIdx.x * blockDim.x + threadIdx.x; i < n4; i += stride) {
        fvec4 v = __builtin_nontemporal_load(src + i);
        usvec4 o;
        o.x = f2bf(v.x); o.y = f2bf(v.y); o.z = f2bf(v.z); o.w = f2bf(v.w);
        dst[i] = o;
    }
}

#define GLOBAL_TO_LDS(gp, lp)                                                  \
    __builtin_amdgcn_global_load_lds(                                          \
        (__attribute__((address_space(1))) const void*)(gp),                   \
        (__attribute__((address_space(3))) void*)(lp), 16, 0, 0)

#define BAR() __builtin_amdgcn_s_barrier()
#define SCHEDB() __builtin_amdgcn_sched_barrier(0)
#define LGKM(n) do { asm volatile("s_waitcnt lgkmcnt(" #n ")" ::: "memory"); SCHEDB(); } while (0)
#define VMW(n) asm volatile("s_waitcnt vmcnt(" #n ")" ::: "memory")

// bijective XCD-aware block remap (m204). gridDim.x == 16 always here.
__device__ __forceinline__ void remap_block(int gy, int& bx, int& by) {
    int nwg = gy << 4;
    int orig = blockIdx.y * 16 + blockIdx.x;
    int q = nwg >> 3, r = nwg & 7;
    int xcd = orig & 7, lid = orig >> 3;
    int wg = (xcd < r ? xcd * (q + 1) : r * (q + 1) + (xcd - r) * q) + lid;
    bx = wg & 15;
    by = wg >> 4;
}

// One K-tile iteration. In scope: lds, t, aoff, boff, ah0[4], ah1[4],
// bfA[4], bfB[4], qA[4], qB[4], acc[8][4], pa0, pa1, pq0, pq1, Kt.
// BFC/BFN: current/next B frag sets. WSRC: reg set holding Bf32(kt+2)
// (written to LDS this iter). WDST: reg set receiving Bf32(kt+3).
#define KITER(KT_, BFC, BFN, WSRC, WDST, VM_, MID_, WR_, LD_, RA_)             \
  do {                                                                         \
    LGKM(4); /* ah0,BFC of kt done; ah1(kt) in flight */                       \
    __builtin_amdgcn_s_setprio(1);                                             \
    _Pragma("unroll") for (int mi = 0; mi < 4; ++mi)                           \
      _Pragma("unroll") for (int ni = 0; ni < 4; ++ni)                         \
        acc[mi][ni] = __builtin_amdgcn_mfma_f32_16x16x32_bf16(                 \
            ah0[mi], BFC[ni], acc[mi][ni], 0, 0, 0);                           \
    __builtin_amdgcn_s_setprio(0);                                             \
    SCHEDB();                                                                  \
    VMW(VM_); /* A(kt+1) in LDS; Bf32(kt+2) in WSRC regs */                    \
    BAR();                                                                     \
    if (LD_) {                                                                 \
      WDST[0] = pq0[0]; WDST[1] = pq0[1];                                      \
      WDST[2] = pq1[0]; WDST[3] = pq1[1];                                      \
      pq0 += 8; pq1 += 8;                                                      \
      SCHEDB();                                                                \
      unsigned short* Aw = lds + ((((KT_) + 3) & 3) << 13);                    \
      GLOBAL_TO_LDS(pa0, Aw + t * 8);                                          \
      GLOBAL_TO_LDS(pa1, Aw + 4096 + t * 8);                                   \
      pa0 += 32; pa1 += 32;                                                    \
      SCHEDB();                                                                \
    }                                                                          \
    if (WR_) {                                                                 \
      unsigned short* Bw = lds + 32768 + ((((KT_) + 2) & 3) << 13);            \
      u32x4 lo, hi;                                                            \
      lo.x = pkbf(WSRC[0].x, WSRC[0].y); lo.y = pkbf(WSRC[0].z, WSRC[0].w);    \
      lo.z = pkbf(WSRC[1].x, WSRC[1].y); lo.w = pkbf(WSRC[1].z, WSRC[1].w);    \
      hi.x = pkbf(WSRC[2].x, WSRC[2].y); hi.y = pkbf(WSRC[2].z, WSRC[2].w);    \
      hi.z = pkbf(WSRC[3].x, WSRC[3].y); hi.w = pkbf(WSRC[3].z, WSRC[3].w);    \
      *(u32x4*)(Bw + t * 8) = lo;                                              \
      *(u32x4*)(Bw + 4096 + t * 8) = hi;                                       \
      SCHEDB();                                                                \
    }                                                                          \
    if (RA_) {                                                                 \
      const unsigned short* Aq = lds + ((((KT_) + 1) & 3) << 13);              \
      const unsigned short* Bq = lds + 32768 + ((((KT_) + 1) & 3) << 13);      \
      _Pragma("unroll") for (int i = 0; i < 4; ++i)                            \
        ah0[i] = *(const short8*)(Aq + aoff + i * 512);                        \
      _Pragma("unroll") for (int n = 0; n < 4; ++n)                            \
        BFN[n] = *(const short8*)(Bq + boff + n * 512);                        \
    }                                                                          \
    LGKM(MID_); /* ah1(kt) done; W+R fly */                                    \
    __builtin_amdgcn_s_setprio(1);                                             \
    _Pragma("unroll") for (int mi = 0; mi < 4; ++mi)                           \
      _Pragma("unroll") for (int ni = 0; ni < 4; ++ni)                         \
        acc[4 + mi][ni] = __builtin_amdgcn_mfma_f32_16x16x32_bf16(             \
            ah1[mi], BFC[ni], acc[4 + mi][ni], 0, 0, 0);                       \
    __builtin_amdgcn_s_setprio(0);                                             \
    SCHEDB();                                                                  \
    if (RA_) {                                                                 \
      const unsigned short* Aq = lds + ((((KT_) + 1) & 3) << 13);              \
      _Pragma("unroll") for (int i = 0; i < 4; ++i)                            \
        ah1[i] = *(const short8*)(Aq + aoff + (4 + i) * 512);                  \
      SCHEDB();                                                                \
    }                                                                          \
  } while (0)

// Prologue: issue Bf32(0,1,2) reg-loads + A-glds(0,1,2); full drain (once per
// kernel, order-assumption-free); write B(0),B(1) LDS; B(2) stays in qA.
#define KPRO()                                                                 \
  do {                                                                         \
    wP0[0] = pq0[0]; wP0[1] = pq0[1]; wP0[2] = pq1[0]; wP0[3] = pq1[1];        \
    pq0 += 8; pq1 += 8;                                                        \
    wP1[0] = pq0[0]; wP1[1] = pq0[1]; wP1[2] = pq1[0]; wP1[3] = pq1[1];        \
    pq0 += 8; pq1 += 8;                                                        \
    qA[0] = pq0[0]; qA[1] = pq0[1]; qA[2] = pq1[0]; qA[3] = pq1[1];            \
    pq0 += 8; pq1 += 8;                                                        \
    SCHEDB();                                                                  \
    _Pragma("unroll") for (int s = 0; s < 3; ++s) {                            \
      unsigned short* Aw = lds + (s << 13);                                    \
      GLOBAL_TO_LDS(pa0, Aw + t * 8);                                          \
      GLOBAL_TO_LDS(pa1, Aw + 4096 + t * 8);                                   \
      pa0 += 32; pa1 += 32;                                                    \
    }                                                                          \
    VMW(0);                                                                    \
    {                                                                          \
      unsigned short* Bw = lds + 32768;                                        \
      u32x4 lo, hi;                                                            \
      lo.x = pkbf(wP0[0].x, wP0[0].y); lo.y = pkbf(wP0[0].z, wP0[0].w);        \
      lo.z = pkbf(wP0[1].x, wP0[1].y); lo.w = pkbf(wP0[1].z, wP0[1].w);        \
      hi.x = pkbf(wP0[2].x, wP0[2].y); hi.y = pkbf(wP0[2].z, wP0[2].w);        \
      hi.z = pkbf(wP0[3].x, wP0[3].y); hi.w = pkbf(wP0[3].z, wP0[3].w);        \
      *(u32x4*)(Bw + t * 8) = lo;                                              \
      *(u32x4*)(Bw + 4096 + t * 8) = hi;                                       \
      Bw = lds + 32768 + 8192;                                                 \
      lo.x = pkbf(wP1[0].x, wP1[0].y); lo.y = pkbf(wP1[0].z, wP1[0].w);        \
      lo.z = pkbf(wP1[1].x, wP1[1].y); lo.w = pkbf(wP1[1].z, wP1[1].w);        \
      hi.x = pkbf(wP1[2].x, wP1[2].y); hi.y = pkbf(wP1[2].z, wP1[2].w);        \
      hi.z = pkbf(wP1[3].x, wP1[3].y); hi.w = pkbf(wP1[3].z, wP1[3].w);        \
      *(u32x4*)(Bw + t * 8) = lo;                                              \
      *(u32x4*)(Bw + 4096 + t * 8) = hi;                                       \
    }                                                                          \
    LGKM(0);                                                                   \
    BAR();                                                                     \
    _Pragma("unroll") for (int i = 0; i < 4; ++i)                              \
      ah0[i] = *(const short8*)(lds + aoff + i * 512);                         \
    _Pragma("unroll") for (int n = 0; n < 4; ++n)                              \
      bfA[n] = *(const short8*)(lds + 32768 + boff + n * 512);                 \
    _Pragma("unroll") for (int i = 0; i < 4; ++i)                              \
      ah1[i] = *(const short8*)(lds + aoff + (4 + i) * 512);                   \
    SCHEDB();                                                                  \
  } while (0)

// Main loop: Kt even, Kt >= 8.
// Steady: VMW(2), LGKM mid 10. Tail: last loads at Kt-4, last write at Kt-3.
#define KLOOP()                                                                \
  do {                                                                         \
    int kt = 0;                                                                \
    for (; kt < Kt - 4; kt += 2) {                                             \
      KITER(kt, bfA, bfB, qA, qB, 2, 10, 1, 1, 1);                             \
      KITER(kt + 1, bfB, bfA, qB, qA, 2, 10, 1, 1, 1);                         \
    }                                                                          \
    KITER(kt, bfA, bfB, qA, qB, 2, 10, 1, 1, 1); ++kt; /* Kt-4 */              \
    KITER(kt, bfB, bfA, qB, qA, 2, 10, 1, 0, 1); ++kt; /* Kt-3 */              \
    KITER(kt, bfA, bfB, qA, qB, 0, 8, 0, 0, 1); ++kt;  /* Kt-2 */              \
    KITER(kt, bfB, bfA, qB, qA, 0, 0, 0, 0, 0);        /* Kt-1 */              \
  } while (0)

// ---------------------------------------------------------------------------
// gemm1: X[4096 x K] @ [Gw;Uw]^T (16-row interleave via addressing), SwiGLU
// epilogue -> inter bf16. 256(M) x 256(combined N) tile, 8 waves (2M x 4N),
// BK=32, 4-deep bufs. B dequantized in-kernel from f32.
// ---------------------------------------------------------------------------
__global__ __launch_bounds__(512, 2)
void gemm1_swiglu(const unsigned short* __restrict__ Xb,
                  const float* __restrict__ Gw,
                  const float* __restrict__ Uw,
                  unsigned short* __restrict__ inter,
                  const float* __restrict__ gs_p,
                  const float* __restrict__ us_p,
                  int K, int I, int gy) {
    extern __shared__ unsigned short lds[];  // A: 4x8192 shorts, B: +32768

    int bx, by;
    remap_block(gy, bx, by);

    const int t = threadIdx.x;
    const int lane = t & 63;
    const int wid = t >> 6;
    const int wm = (wid >> 2) * 128;
    const int wn = (wid & 3) * 64;
    const int fr = lane & 15;
    const int ca = (((lane >> 4) ^ ((fr >> 1) & 3)) << 3);

    const int m_base = bx * 256;

    // staging: thread t covers row r=t>>2 (+128), k-group g (pre-swizzled)
    const int g = (t & 3) ^ ((t >> 3) & 3);
    const int rl = t >> 2;
    const unsigned short* pa0 = Xb + (size_t)(m_base + rl) * K + g * 8;
    const unsigned short* pa1 = pa0 + (size_t)128 * K;

    // combined row cg: bit4 selects gate/up (16-row interleave, R9 epilogue)
    const int cg = by * 256 + rl;
    const float* wbase = ((cg >> 4) & 1) ? Uw : Gw;
    const int srow = ((cg >> 5) << 4) + (cg & 15);
    const u32x4* pq0 = (const u32x4*)(wbase + (size_t)srow * K) + 2 * g;
    const u32x4* pq1 = pq0 + (size_t)16 * K;   // +64 source rows (cg+128)

    f32x4 acc[8][4];
    const f32x4 z = {0.0f, 0.0f, 0.0f, 0.0f};
#pragma unroll
    for (int i = 0; i < 8; ++i)
#pragma unroll
        for (int j = 0; j < 4; ++j) acc[i][j] = z;

    const int aoff = (wm + fr) * 32 + ca;
    const int boff = (wn + fr) * 32 + ca;
    const int Kt = K >> 5;   // 128

    short8 ah0[4], ah1[4], bfA[4], bfB[4];
    u32x4 qA[4], qB[4], wP0[4], wP1[4];

    KPRO();
    KLOOP();

    // ---- SwiGLU epilogue: even 16-frag = gate, odd = up (R9-verified) ----
    const float gsc = *gs_p;
    const float usc = *us_p;
    const int row0 = m_base + wm + ((lane >> 4) << 2);
    const int col0 = by * 128 + (wn >> 1) + fr;
#pragma unroll
    for (int mi = 0; mi < 8; ++mi)
#pragma unroll
        for (int p = 0; p < 2; ++p)
#pragma unroll
            for (int r = 0; r < 4; ++r) {
                float gg = acc[mi][2 * p][r] * gsc;
                float uu = acc[mi][2 * p + 1][r] * usc;
                float s = gg / (1.0f + __expf(-gg));   // silu
                inter[(size_t)(row0 + mi * 16 + r) * I + (col0 + p * 16)] =
                    f2bf(s * uu);
            }
}

// ---------------------------------------------------------------------------
// gemm2: inter[4096 x I] @ Dw[H x I]^T * ds -> out f32. Same pipeline.
// ---------------------------------------------------------------------------
__global__ __launch_bounds__(512, 2)
void gemm2_down(const unsigned short* __restrict__ Ab,
                const float* __restrict__ Dw,
                float* __restrict__ out,
                const float* __restrict__ ds_p,
                int K, int H, int gy) {
    extern __shared__ unsigned short lds[];

    int bx, by;
    remap_block(gy, bx, by);

    const int t = threadIdx.x;
    const int lane = t & 63;
    const int wid = t >> 6;
    const int wm = (wid >> 2) * 128;
    const int wn = (wid & 3) * 64;
    const int fr = lane & 15;
    const int ca = (((lane >> 4) ^ ((fr >> 1) & 3)) << 3);

    const int m_base = bx * 256;
    const long b_row0 = (long)by * 256;

    const int g = (t & 3) ^ ((t >> 3) & 3);
    const int rl = t >> 2;
    const unsigned short* pa0 = Ab + (size_t)(m_base + rl) * K + g * 8;
    const unsigned short* pa1 = pa0 + (size_t)128 * K;

    const u32x4* pq0 = (const u32x4*)(Dw + (size_t)(b_row0 + rl) * K) + 2 * g;
    const u32x4* pq1 = pq0 + (size_t)32 * K;   // +128 rows

    f32x4 acc[8][4];
    const f32x4 z = {0.0f, 0.0f, 0.0f, 0.0f};
#pragma unroll
    for (int i = 0; i < 8; ++i)
#pragma unroll
        for (int j = 0; j < 4; ++j) acc[i][j] = z;

    const int aoff = (wm + fr) * 32 + ca;
    const int boff = (wn + fr) * 32 + ca;
    const int Kt = K >> 5;   // 344

    short8 ah0[4], ah1[4], bfA[4], bfB[4];
    u32x4 qA[4], qB[4], wP0[4], wP1[4];

    KPRO();
    KLOOP();

    const float dsc = *ds_p;
    const int row0 = m_base + wm + ((lane >> 4) << 2);
    const int col0 = by * 256 + wn + fr;
#pragma unroll
    for (int mi = 0; mi < 8; ++mi)
#pragma unroll
        for (int ni = 0; ni < 4; ++ni)
#pragma unroll
            for (int r = 0; r < 4; ++r)
                out[(size_t)(row0 + mi * 16 + r) * H + (col0 + ni * 16)] =
                    acc[mi][ni][r] * dsc;
}

extern "C" void kernel_launch(void* const* d_in, const int* in_sizes, int n_in,
                              void* d_out, int out_size, void* d_ws, size_t ws_size,
                              hipStream_t stream) {
    (void)in_sizes; (void)n_in; (void)out_size;
    const float* x  = (const float*)d_in[0];
    const float* gw = (const float*)d_in[1];
    const float* uw = (const float*)d_in[2];
    const float* dw = (const float*)d_in[3];
    const float* gs = (const float*)d_in[4];
    const float* us = (const float*)d_in[5];
    const float* ds = (const float*)d_in[6];
    float* out = (float*)d_out;

    const long M = 4096;    // BATCH*SEQ
    const long Kh = 4096;   // HIDDEN
    const long I = 11008;   // INTER
    const long H = 4096;

    (void)hipFuncSetAttribute(reinterpret_cast<const void*>(gemm1_swiglu),
                              hipFuncAttributeMaxDynamicSharedMemorySize, 131072);
    (void)hipFuncSetAttribute(reinterpret_cast<const void*>(gemm2_down),
                              hipFuncAttributeMaxDynamicSharedMemorySize, 131072);

    char* ws = (char*)d_ws;
    unsigned short* Xb = (unsigned short*)ws;                       // M*Kh bf16
    unsigned short* inter = (unsigned short*)(ws + (size_t)M * Kh * 2);
    const size_t used = (size_t)M * Kh * 2 + (size_t)M * I * 2;     // ~124 MB
    if (ws_size < used) return;

    // ---- x -> bf16 (the only convert left) ----
    {
        long n4 = M * Kh / 4;
        cvt_f32_bf16<<<dim3(2048), dim3(256), 0, stream>>>(
            (const fvec4*)x, (usvec4*)Xb, n4);
    }

    // ---- gemm1: single launch, weights dequantized in-kernel ----
    // combined N = 2*I = 22016 -> 86 tiles of 256
    gemm1_swiglu<<<dim3(16, 86), dim3(512), 131072, stream>>>(
        Xb, gw, uw, inter, gs, us, (int)Kh, (int)I, 86);

    // ---- gemm2: single launch, weights dequantized in-kernel ----
    gemm2_down<<<dim3(16, 16), dim3(512), 131072, stream>>>(
        inter, dw, out, ds, (int)I, (int)H, 16);
}

// Round 7
// 1378.664 us; speedup vs baseline: 1.4891x; 1.4891x over previous
//
#include <hip/hip_runtime.h>

// BitNet MLP: out = (silu(x@Gw^T * gs) * (x@Uw^T * us)) @ Dw^T * ds
// M=4096 tokens, K=4096 hidden, I=11008 inter. Ternary weights -> exact in bf16.
//
// R13: R9's verified components (16x16x32 frag pattern w/ 0-conflict swizzle,
// gload_lds staging, epilogues, converts, launcher) restructured into the
// m201 8-phase schedule: group = 4 phases = 64-K (tiles 2g,2g+1 = kk dim).
// Per phase: ds_reads {12,4,8,0} -> 2x global_load_lds -> BAR -> lgkm(0)+
// sched_barrier -> setprio(1) 16 MFMA setprio(0) -> BAR. Stage order matches
// read completion: P1/P2 stage A(2g+2),A(2g+3) (opposite buf pair, read done
// a group ago); P3/P4 stage B(2g+4),B(2g+5) (current pair, B reads done at
// P2-end barrier). Counted VMW(4) once per group: drains exactly the tiles
// group g+1 reads, leaves 2 B-halves in flight (never 0 until tail).
// Mechanism (m201/m218b): phases create cross-wave role-split so ds_reads of
// one wave overlap MFMA of its SIMD-mate; setprio arbitrates.

typedef short short8 __attribute__((ext_vector_type(8)));
typedef float f32x4 __attribute__((ext_vector_type(4)));
typedef float fvec4 __attribute__((ext_vector_type(4)));
typedef unsigned short usvec4 __attribute__((ext_vector_type(4)));

__device__ __forceinline__ unsigned short f2bf(float f) {
    unsigned int u = __float_as_uint(f);
    u += 0x7FFFu + ((u >> 16) & 1u);   // round-to-nearest-even
    return (unsigned short)(u >> 16);
}

__global__ void cvt_f32_bf16(const fvec4* __restrict__ src,
                             usvec4* __restrict__ dst, long n4) {
    long stride = (long)gridDim.x * blockDim.x;
    for (long i = (long)blockIdx.x * blockDim.x + threadIdx.x; i < n4; i += stride) {
        fvec4 v = __builtin_nontemporal_load(src + i);
        usvec4 o;
        o.x = f2bf(v.x); o.y = f2bf(v.y); o.z = f2bf(v.z); o.w = f2bf(v.w);
        dst[i] = o;
    }
}

// Convert gate+up, interleave at 16-row granularity: combined rows
// [32b..32b+16) = gate rows [16b..16b+16), [32b+16..32b+32) = up rows.
__global__ void cvt2_f32_bf16_ilv(const fvec4* __restrict__ s0,
                                  const fvec4* __restrict__ s1,
                                  usvec4* __restrict__ d, long n4) {
    long stride = (long)gridDim.x * blockDim.x;
    for (long i = (long)blockIdx.x * blockDim.x + threadIdx.x; i < n4; i += stride) {
        long j = i >> 10;          // local inter row
        long c = i & 1023;
        long Rg = ((j & ~15L) << 1) | (j & 15);
        fvec4 a = __builtin_nontemporal_load(s0 + i);
        fvec4 b = __builtin_nontemporal_load(s1 + i);
        usvec4 oa, ob;
        oa.x = f2bf(a.x); oa.y = f2bf(a.y); oa.z = f2bf(a.z); oa.w = f2bf(a.w);
        ob.x = f2bf(b.x); ob.y = f2bf(b.y); ob.z = f2bf(b.z); ob.w = f2bf(b.w);
        d[Rg * 1024 + c] = oa;
        d[(Rg + 16) * 1024 + c] = ob;
    }
}

#define GLOBAL_TO_LDS(gp, lp)                                                  \
    __builtin_amdgcn_global_load_lds(                                          \
        (__attribute__((address_space(1))) const void*)(gp),                   \
        (__attribute__((address_space(3))) void*)(lp), 16, 0, 0)

#define BAR() __builtin_amdgcn_s_barrier()
#define SCHEDB() __builtin_amdgcn_sched_barrier(0)
#define LGKM(n) do { asm volatile("s_waitcnt lgkmcnt(" #n ")" ::: "memory"); SCHEDB(); } while (0)
#define VMW(n) asm volatile("s_waitcnt vmcnt(" #n ")" ::: "memory")

// bijective XCD-aware block remap (m204). gridDim.x == 16 always here.
__device__ __forceinline__ void remap_block(int gy, int& bx, int& by) {
    int nwg = gy << 4;
    int orig = blockIdx.y * 16 + blockIdx.x;
    int q = nwg >> 3, r = nwg & 7;
    int xcd = orig & 7, lid = orig >> 3;
    int wg = (xcd < r ? xcd * (q + 1) : r * (q + 1) + (xcd - r) * q) + lid;
    bx = wg & 15;
    by = wg >> 4;
}

// 16-MFMA cluster for quadrant (MH,NH). kk selects the tile (C0/C1 halves of
// the 64-K group). acc row index = MH*4+mi (rows wm+(MH*4+mi)*16, same layout
// as R9), col index = NH*2+ni.
#define MFMA16(AH, BH, MH, NH)                                                \
  do {                                                                        \
    __builtin_amdgcn_s_setprio(1);                                            \
    _Pragma("unroll") for (int kk = 0; kk < 2; ++kk)                          \
      _Pragma("unroll") for (int mi = 0; mi < 4; ++mi)                        \
        _Pragma("unroll") for (int ni = 0; ni < 2; ++ni)                      \
          acc[(MH)*4+mi][(NH)*2+ni] =                                         \
              __builtin_amdgcn_mfma_f32_16x16x32_bf16(                        \
                  AH[kk*4+mi], BH[kk*2+ni], acc[(MH)*4+mi][(NH)*2+ni],        \
                  0, 0, 0);                                                   \
    __builtin_amdgcn_s_setprio(0);                                            \
    SCHEDB();                                                                 \
  } while (0)

// One 4-phase group computing tiles 2g (buf C0), 2g+1 (buf C1).
// SA: stage A(2g+2)->buf C0^2, A(2g+3)->buf C1^2 at P1,P2.
// SB: stage B(2g+4)->buf C0,   B(2g+5)->buf C1   at P3,P4.
// TOK: 2 -> VMW(4) at P4 (steady), 1 -> VMW(0), 0 -> none.
#define KGROUP(C0, C1, SA, SB, TOK)                                           \
  do {                                                                        \
    /* ---- P1: A[mh0] both tiles (8) + B[nh0] both (4); stage A(2g+2) */     \
    { const unsigned short* Aq0 = lds + (C0) * 8192;                          \
      const unsigned short* Aq1 = lds + (C1) * 8192;                          \
      const unsigned short* Bq0 = lds + 32768 + (C0) * 8192;                  \
      const unsigned short* Bq1 = lds + 32768 + (C1) * 8192;                  \
      _Pragma("unroll") for (int mi = 0; mi < 4; ++mi) {                      \
        a0[mi]     = *(const short8*)(Aq0 + aoff + mi * 512);                 \
        a0[4 + mi] = *(const short8*)(Aq1 + aoff + mi * 512);                 \
      }                                                                       \
      _Pragma("unroll") for (int ni = 0; ni < 2; ++ni) {                      \
        b0[ni]     = *(const short8*)(Bq0 + boff + ni * 512);                 \
        b0[2 + ni] = *(const short8*)(Bq1 + boff + ni * 512);                 \
      }                                                                       \
    }                                                                         \
    if (SA) {                                                                 \
      GLOBAL_TO_LDS(pa0, lds + ((C0) ^ 2) * 8192 + t * 8);                    \
      GLOBAL_TO_LDS(pa1, lds + ((C0) ^ 2) * 8192 + 4096 + t * 8);             \
      pa0 += 32; pa1 += 32;                                                   \
    }                                                                         \
    LGKM(8); BAR(); LGKM(0);                                                  \
    MFMA16(a0, b0, 0, 0);                                                     \
    BAR();                                                                    \
    /* ---- P2: B[nh1] both (4); stage A(2g+3) */                             \
    { const unsigned short* Bq0 = lds + 32768 + (C0) * 8192;                  \
      const unsigned short* Bq1 = lds + 32768 + (C1) * 8192;                  \
      _Pragma("unroll") for (int ni = 0; ni < 2; ++ni) {                      \
        b1[ni]     = *(const short8*)(Bq0 + boff + (2 + ni) * 512);           \
        b1[2 + ni] = *(const short8*)(Bq1 + boff + (2 + ni) * 512);           \
      }                                                                       \
    }                                                                         \
    if (SA) {                                                                 \
      GLOBAL_TO_LDS(pa0, lds + ((C1) ^ 2) * 8192 + t * 8);                    \
      GLOBAL_TO_LDS(pa1, lds + ((C1) ^ 2) * 8192 + 4096 + t * 8);             \
      pa0 += 32; pa1 += 32;                                                   \
    }                                                                         \
    BAR(); LGKM(0);                                                           \
    MFMA16(a0, b1, 0, 1);                                                     \
    BAR();                                                                    \
    /* ---- P3: A[mh1] both (8); stage B(2g+4) (B of tile 2g: reads done) */  \
    { const unsigned short* Aq0 = lds + (C0) * 8192;                          \
      const unsigned short* Aq1 = lds + (C1) * 8192;                          \
      _Pragma("unroll") for (int mi = 0; mi < 4; ++mi) {                      \
        a1[mi]     = *(const short8*)(Aq0 + aoff + (4 + mi) * 512);           \
        a1[4 + mi] = *(const short8*)(Aq1 + aoff + (4 + mi) * 512);           \
      }                                                                       \
    }                                                                         \
    if (SB) {                                                                 \
      GLOBAL_TO_LDS(pb0, lds + 32768 + (C0) * 8192 + t * 8);                  \
      GLOBAL_TO_LDS(pb1, lds + 32768 + (C0) * 8192 + 4096 + t * 8);           \
      pb0 += 32; pb1 += 32;                                                   \
    }                                                                         \
    BAR(); LGKM(0);                                                           \
    MFMA16(a1, b1, 1, 1);                                                     \
    BAR();                                                                    \
    /* ---- P4: stage B(2g+5); counted vmcnt; MFMA (1,0) from live regs */    \
    if (SB) {                                                                 \
      GLOBAL_TO_LDS(pb0, lds + 32768 + (C1) * 8192 + t * 8);                  \
      GLOBAL_TO_LDS(pb1, lds + 32768 + (C1) * 8192 + 4096 + t * 8);           \
      pb0 += 32; pb1 += 32;                                                   \
    }                                                                         \
    if ((TOK) == 2) { VMW(4); } else if ((TOK) == 1) { VMW(0); }              \
    BAR();                                                                    \
    MFMA16(a1, b0, 1, 0);                                                     \
    BAR();                                                                    \
  } while (0)

// Prologue: stage A0,B0,A1,B1,B2,B3 (12 gloads; B2,B3 last in FIFO), then
// VMW(4) leaves B2,B3 in flight; tiles 0,1 fully landed.
#define KPRO8()                                                               \
  do {                                                                        \
    GLOBAL_TO_LDS(pa0, lds + t * 8);                                          \
    GLOBAL_TO_LDS(pa1, lds + 4096 + t * 8);                                   \
    pa0 += 32; pa1 += 32;                                                     \
    GLOBAL_TO_LDS(pb0, lds + 32768 + t * 8);                                  \
    GLOBAL_TO_LDS(pb1, lds + 32768 + 4096 + t * 8);                           \
    pb0 += 32; pb1 += 32;                                                     \
    GLOBAL_TO_LDS(pa0, lds + 8192 + t * 8);                                   \
    GLOBAL_TO_LDS(pa1, lds + 8192 + 4096 + t * 8);                            \
    pa0 += 32; pa1 += 32;                                                     \
    GLOBAL_TO_LDS(pb0, lds + 32768 + 8192 + t * 8);                           \
    GLOBAL_TO_LDS(pb1, lds + 32768 + 8192 + 4096 + t * 8);                    \
    pb0 += 32; pb1 += 32;                                                     \
    GLOBAL_TO_LDS(pb0, lds + 32768 + 16384 + t * 8);                          \
    GLOBAL_TO_LDS(pb1, lds + 32768 + 16384 + 4096 + t * 8);                   \
    pb0 += 32; pb1 += 32;                                                     \
    GLOBAL_TO_LDS(pb0, lds + 32768 + 24576 + t * 8);                          \
    GLOBAL_TO_LDS(pb1, lds + 32768 + 24576 + 4096 + t * 8);                   \
    pb0 += 32; pb1 += 32;                                                     \
    VMW(4); BAR();                                                            \
  } while (0)

// Main loop over G = Kt/2 groups (G even, >= 4). Steady SA=SB=1,TOK=2;
// group G-2: SA=1,SB=0,TOK=1 (drain); group G-1: nothing.
#define KLOOP8()                                                              \
  do {                                                                        \
    for (int g = 0; g < G - 2; g += 2) {                                      \
      KGROUP(0, 1, 1, 1, 2);                                                  \
      KGROUP(2, 3, 1, 1, 2);                                                  \
    }                                                                         \
    KGROUP(0, 1, 1, 0, 1);                                                    \
    KGROUP(2, 3, 0, 0, 0);                                                    \
  } while (0)

// ---------------------------------------------------------------------------
// gemm1: X[4096 x K] @ [Gw;Uw interleaved-16]^T, SwiGLU epilogue -> inter bf16
// 256(M) x 256(combined N) tile, 8 waves (2M x 4N), 4x 32-K bufs, 128KB LDS.
// ---------------------------------------------------------------------------
__global__ __launch_bounds__(512, 2)
void gemm1_swiglu(const unsigned short* __restrict__ Xb,
                  const unsigned short* __restrict__ Wc,
                  unsigned short* __restrict__ inter,
                  const float* __restrict__ gs_p,
                  const float* __restrict__ us_p,
                  int K, int I, int n0, int gy) {
    extern __shared__ unsigned short lds[];  // A: 4x8192 shorts, B: +32768

    int bx, by;
    remap_block(gy, bx, by);

    const int t = threadIdx.x;
    const int lane = t & 63;
    const int wid = t >> 6;
    const int wm = (wid >> 2) * 128;
    const int wn = (wid & 3) * 64;
    const int fr = lane & 15;
    const int ca = (((lane >> 4) ^ ((fr >> 1) & 3)) << 3);

    const int m_base = bx * 256;
    const long b_row0 = (long)by * 256;

    const int colsw = (((t & 3) ^ ((t >> 3) & 3)) << 3);
    const unsigned short* pa0 = Xb + (size_t)(m_base + (t >> 2)) * K + colsw;
    const unsigned short* pa1 = pa0 + (size_t)128 * K;
    const unsigned short* pb0 = Wc + (size_t)(b_row0 + (t >> 2)) * K + colsw;
    const unsigned short* pb1 = pb0 + (size_t)128 * K;

    f32x4 acc[8][4];
    const f32x4 z = {0.0f, 0.0f, 0.0f, 0.0f};
#pragma unroll
    for (int i = 0; i < 8; ++i)
#pragma unroll
        for (int j = 0; j < 4; ++j) acc[i][j] = z;

    const int aoff = (wm + fr) * 32 + ca;
    const int boff = (wn + fr) * 32 + ca;
    const int G = K >> 6;   // 64 groups of 64-K

    short8 a0[8], a1[8], b0[4], b1[4];

    KPRO8();
    KLOOP8();

    // ---- SwiGLU epilogue: even 16-frag = gate, odd = up (R9-verified) ----
    const float gsc = *gs_p;
    const float usc = *us_p;
    const int row0 = m_base + wm + ((lane >> 4) << 2);
    const int col0 = n0 + by * 128 + (wn >> 1) + fr;
#pragma unroll
    for (int mi = 0; mi < 8; ++mi)
#pragma unroll
        for (int p = 0; p < 2; ++p)
#pragma unroll
            for (int r = 0; r < 4; ++r) {
                float g = acc[mi][2 * p][r] * gsc;
                float u = acc[mi][2 * p + 1][r] * usc;
                float s = g / (1.0f + __expf(-g));   // silu
                inter[(size_t)(row0 + mi * 16 + r) * I + (col0 + p * 16)] =
                    f2bf(s * u);
            }
}

// ---------------------------------------------------------------------------
// gemm2: inter[4096 x I] @ Dw[H x I]^T * ds -> out f32. Same schedule.
// ---------------------------------------------------------------------------
__global__ __launch_bounds__(512, 2)
void gemm2_down(const unsigned short* __restrict__ Ab,
                const unsigned short* __restrict__ Dw,
                float* __restrict__ out,
                const float* __restrict__ ds_p,
                int K, int H, int n0, int gy) {
    extern __shared__ unsigned short lds[];

    int bx, by;
    remap_block(gy, bx, by);

    const int t = threadIdx.x;
    const int lane = t & 63;
    const int wid = t >> 6;
    const int wm = (wid >> 2) * 128;
    const int wn = (wid & 3) * 64;
    const int fr = lane & 15;
    const int ca = (((lane >> 4) ^ ((fr >> 1) & 3)) << 3);

    const int m_base = bx * 256;
    const long b_row0 = (long)by * 256;

    const int colsw = (((t & 3) ^ ((t >> 3) & 3)) << 3);
    const unsigned short* pa0 = Ab + (size_t)(m_base + (t >> 2)) * K + colsw;
    const unsigned short* pa1 = pa0 + (size_t)128 * K;
    const unsigned short* pb0 = Dw + (size_t)(b_row0 + (t >> 2)) * K + colsw;
    const unsigned short* pb1 = pb0 + (size_t)128 * K;

    f32x4 acc[8][4];
    const f32x4 z = {0.0f, 0.0f, 0.0f, 0.0f};
#pragma unroll
    for (int i = 0; i < 8; ++i)
#pragma unroll
        for (int j = 0; j < 4; ++j) acc[i][j] = z;

    const int aoff = (wm + fr) * 32 + ca;
    const int boff = (wn + fr) * 32 + ca;
    const int G = K >> 6;   // 172 groups

    short8 a0[8], a1[8], b0[4], b1[4];

    KPRO8();
    KLOOP8();

    const float dsc = *ds_p;
    const int row0 = m_base + wm + ((lane >> 4) << 2);
    const int col0 = n0 + by * 256 + wn + fr;
#pragma unroll
    for (int mi = 0; mi < 8; ++mi)
#pragma unroll
        for (int ni = 0; ni < 4; ++ni)
#pragma unroll
            for (int r = 0; r < 4; ++r)
                out[(size_t)(row0 + mi * 16 + r) * H + (col0 + ni * 16)] =
                    acc[mi][ni][r] * dsc;
}

extern "C" void kernel_launch(void* const* d_in, const int* in_sizes, int n_in,
                              void* d_out, int out_size, void* d_ws, size_t ws_size,
                              hipStream_t stream) {
    (void)in_sizes; (void)n_in; (void)out_size;
    const float* x  = (const float*)d_in[0];
    const float* gw = (const float*)d_in[1];
    const float* uw = (const float*)d_in[2];
    const float* dw = (const float*)d_in[3];
    const float* gs = (const float*)d_in[4];
    const float* us = (const float*)d_in[5];
    const float* ds = (const float*)d_in[6];
    float* out = (float*)d_out;

    const long M = 4096;    // BATCH*SEQ
    const long Kh = 4096;   // HIDDEN
    const long I = 11008;   // INTER
    const long H = 4096;

    (void)hipFuncSetAttribute(reinterpret_cast<const void*>(gemm1_swiglu),
                              hipFuncAttributeMaxDynamicSharedMemorySize, 131072);
    (void)hipFuncSetAttribute(reinterpret_cast<const void*>(gemm2_down),
                              hipFuncAttributeMaxDynamicSharedMemorySize, 131072);

    char* ws = (char*)d_ws;
    unsigned short* Xb = (unsigned short*)ws;                       // M*Kh bf16
    unsigned short* inter = (unsigned short*)(ws + (size_t)M * Kh * 2);
    const size_t used = (size_t)M * Kh * 2 + (size_t)M * I * 2;     // ~124 MB
    if (ws_size < used + 2 * (size_t)256 * Kh * 2) return;
    char* wbuf = ws + used;
    const size_t avail = ws_size - used;

    // ---- x -> bf16 ----
    {
        long n4 = M * Kh / 4;
        cvt_f32_bf16<<<dim3(2048), dim3(256), 0, stream>>>(
            (const fvec4*)x, (usvec4*)Xb, n4);
    }

    // ---- phase 1: interleaved gate/up convert + fused GEMM1 ----
    long mr1 = (long)(avail / ((size_t)2 * Kh * 2));   // inter cols per chunk
    mr1 = (mr1 / 128) * 128;
    if (mr1 > I) mr1 = I;
    if (mr1 < 128) mr1 = 128;
    unsigned short* Wc = (unsigned short*)wbuf;        // 2*mr1 x Kh interleaved
    for (long n0 = 0; n0 < I; n0 += mr1) {
        long rc = (I - n0 < mr1) ? (I - n0) : mr1;
        cvt2_f32_bf16_ilv<<<dim3(2048), dim3(256), 0, stream>>>(
            (const fvec4*)(gw + n0 * Kh), (const fvec4*)(uw + n0 * Kh),
            (usvec4*)Wc, rc * Kh / 4);
        unsigned gy = (unsigned)(rc / 128);   // combined-N tiles of 256
        gemm1_swiglu<<<dim3(16, gy), dim3(512), 131072, stream>>>(
            Xb, Wc, inter, gs, us, (int)Kh, (int)I, (int)n0, (int)gy);
    }

    // ---- phase 2: down convert + GEMM2 ----
    long mr2 = (long)(avail / ((size_t)I * 2));
    mr2 = (mr2 / 256) * 256;
    if (mr2 > H) mr2 = H;
    if (mr2 < 256) mr2 = 256;
    unsigned short* Wd = (unsigned short*)wbuf;
    for (long h0 = 0; h0 < H; h0 += mr2) {
        long rc = (H - h0 < mr2) ? (H - h0) : mr2;
        cvt_f32_bf16<<<dim3(2048), dim3(256), 0, stream>>>(
            (const fvec4*)(dw + h0 * I), (usvec4*)Wd, rc * I / 4);
        unsigned gy = (unsigned)(rc / 256);
        gemm2_down<<<dim3(16, gy), dim3(512), 131072, stream>>>(
            inter, Wd, out, ds, (int)I, (int)H, (int)h0, (int)gy);
    }
}